// Round 1
// baseline (540.259 us; speedup 1.0000x reference)
//
#include <hip/hip_runtime.h>
#include <hip/hip_bf16.h>
#include <math.h>

typedef __bf16 bf16_t;
typedef __bf16 bf16x8 __attribute__((ext_vector_type(8)));
typedef __bf16 bf16x4 __attribute__((ext_vector_type(4)));
typedef float  f32x4  __attribute__((ext_vector_type(4)));

#define GLD_LDS16(g, l)                                                          \
  __builtin_amdgcn_global_load_lds((const __attribute__((address_space(1))) void*)(g), \
                                   (__attribute__((address_space(3))) void*)(l), 16, 0, 0)

// ---------------- fp32 -> bf16 convert (x4 vectorized) ----------------
__global__ __launch_bounds__(256) void k_cvt_bf16(const float* __restrict__ in,
                                                  bf16_t* __restrict__ out, int n4) {
  int i = blockIdx.x * 256 + threadIdx.x;
  if (i >= n4) return;
  float4 v = reinterpret_cast<const float4*>(in)[i];
  bf16x4 o;
  o[0] = (bf16_t)v.x; o[1] = (bf16_t)v.y; o[2] = (bf16_t)v.z; o[3] = (bf16_t)v.w;
  reinterpret_cast<bf16x4*>(out)[i] = o;
}

// ---------------- build UW = [U_w | W_w] (bf16) + summed bias ----------------
__global__ __launch_bounds__(256) void k_build_uw(const float* __restrict__ U,
                                                  const float* __restrict__ W,
                                                  const float* __restrict__ Ub,
                                                  const float* __restrict__ Wb,
                                                  bf16_t* __restrict__ UW,
                                                  float* __restrict__ buw) {
  int idx = blockIdx.x * 256 + threadIdx.x;   // over 2M/4 elements
  int i = idx * 4;
  int g = i >> 11;          // row (output feature)
  int k = i & 2047;         // col in concatenated K (4-aligned, never straddles 1024)
  const float* src = (k < 1024) ? (U + g * 1024 + k) : (W + g * 1024 + (k - 1024));
  float4 v = *reinterpret_cast<const float4*>(src);
  bf16x4 o;
  o[0] = (bf16_t)v.x; o[1] = (bf16_t)v.y; o[2] = (bf16_t)v.z; o[3] = (bf16_t)v.w;
  reinterpret_cast<bf16x4*>(UW)[idx] = o;
  if (idx < 1024) buw[idx] = Ub[idx] + Wb[idx];
}

// ---------------- GEMM: C[M,N] = relu(A[M,K] @ Bw[N,K]^T + bias[N]) ----------------
// bf16 in / bf16 out, fp32 accum. 128x128 tile, BK=32, 256 threads (4 waves 2x2).
// Staging via global_load_lds(16B) with source-side XOR swizzle kb^=(r>>1)&3 so
// fragment ds_read_b128 is 2-way (free) instead of 8-way bank conflicted.
__global__ __launch_bounds__(256) void k_gemm(const bf16_t* __restrict__ A,
                                              const bf16_t* __restrict__ Bw,
                                              const float* __restrict__ bias,
                                              bf16_t* __restrict__ C,
                                              int M, int K, int N) {
  __shared__ bf16_t As[128 * 32];
  __shared__ bf16_t Bs[128 * 32];

  const int tid  = threadIdx.x;
  const int lane = tid & 63;
  const int wave = tid >> 6;
  const int wr = wave >> 1;      // 0..1  (row half of tile)
  const int wc = wave & 1;       // 0..1  (col half of tile)
  const int bm = blockIdx.x;
  const int bn = blockIdx.y;

  f32x4 acc[4][4] = {};

  const int rl = lane & 15;      // fragment row within 16
  const int kq = lane >> 4;      // k-block 0..3 wanted by this lane

  for (int k0 = 0; k0 < K; k0 += 32) {
    // ---- stage A tile (128x32) ----
#pragma unroll
    for (int it = 0; it < 2; ++it) {
      int c = tid + 256 * it;          // chunk 0..511, 8 bf16 each
      int r = c >> 2;
      int kbp = c & 3;
      int kb = kbp ^ ((r >> 1) & 3);   // inverse swizzle on the global source
      int grow = bm * 128 + r;
      if (grow >= M) grow = M - 1;     // clamp: rows >= M are never stored
      const bf16_t* gsrc = A + (size_t)grow * K + k0 + kb * 8;
      GLD_LDS16(gsrc, As + c * 8);
    }
    // ---- stage B tile (128x32) ----
#pragma unroll
    for (int it = 0; it < 2; ++it) {
      int c = tid + 256 * it;
      int r = c >> 2;
      int kbp = c & 3;
      int kb = kbp ^ ((r >> 1) & 3);
      int grow = bn * 128 + r;         // N always multiple of 128
      const bf16_t* gsrc = Bw + (size_t)grow * K + k0 + kb * 8;
      GLD_LDS16(gsrc, Bs + c * 8);
    }
    __syncthreads();   // drains vmcnt+lgkmcnt

    bf16x8 af[4], bfr[4];
#pragma unroll
    for (int i = 0; i < 4; ++i) {
      int r = wr * 64 + i * 16 + rl;
      int kbp = kq ^ ((r >> 1) & 3);
      af[i] = *reinterpret_cast<const bf16x8*>(As + r * 32 + kbp * 8);
    }
#pragma unroll
    for (int j = 0; j < 4; ++j) {
      int r = wc * 64 + j * 16 + rl;
      int kbp = kq ^ ((r >> 1) & 3);
      bfr[j] = *reinterpret_cast<const bf16x8*>(Bs + r * 32 + kbp * 8);
    }
#pragma unroll
    for (int i = 0; i < 4; ++i)
#pragma unroll
      for (int j = 0; j < 4; ++j)
        acc[i][j] = __builtin_amdgcn_mfma_f32_16x16x32_bf16(af[i], bfr[j], acc[i][j], 0, 0, 0);
    __syncthreads();
  }

  // ---- epilogue: bias + relu + bf16 store ----
  const int rq = lane >> 4;      // C/D: row = rq*4 + reg, col = lane&15
  const int cl = lane & 15;
#pragma unroll
  for (int j = 0; j < 4; ++j) {
    int gcol = bn * 128 + wc * 64 + j * 16 + cl;
    float bv = bias[gcol];
#pragma unroll
    for (int i = 0; i < 4; ++i) {
#pragma unroll
      for (int reg = 0; reg < 4; ++reg) {
        int grow = bm * 128 + wr * 64 + i * 16 + rq * 4 + reg;
        if (grow < M) {
          float v = acc[i][j][reg] + bv;
          v = v > 0.0f ? v : 0.0f;
          C[(size_t)grow * N + gcol] = (bf16_t)v;
        }
      }
    }
  }
}

// ---------------- logits: out[b,o] = root[b,:] . O_w[o,:] + O_b[o] ----------------
__global__ __launch_bounds__(256) void k_logits(const bf16_t* __restrict__ root,
                                                const bf16_t* __restrict__ Ow,
                                                const float* __restrict__ Ob,
                                                float* __restrict__ out) {
  int o = blockIdx.x * 256 + threadIdx.x;   // grid.x = 4
  int b = blockIdx.y;                        // grid.y = 8
  const bf16_t* r = root + b * 1024;
  const bf16_t* w = Ow + (size_t)o * 1024;
  float s = 0.0f;
#pragma unroll 4
  for (int k = 0; k < 1024; k += 8) {
    bf16x8 rv = *reinterpret_cast<const bf16x8*>(r + k);
    bf16x8 wv = *reinterpret_cast<const bf16x8*>(w + k);
#pragma unroll
    for (int j = 0; j < 8; ++j) s += (float)rv[j] * (float)wv[j];
  }
  out[b * 1024 + o] = s + Ob[o];
}

// ---------------- per-row log_softmax (8 rows x 1024) ----------------
__device__ inline float wave_max_f(float v) {
#pragma unroll
  for (int off = 32; off > 0; off >>= 1) v = fmaxf(v, __shfl_xor(v, off, 64));
  return v;
}
__device__ inline float wave_sum_f(float v) {
#pragma unroll
  for (int off = 32; off > 0; off >>= 1) v += __shfl_xor(v, off, 64);
  return v;
}

__global__ __launch_bounds__(256) void k_logsoftmax(const float* __restrict__ logits,
                                                    float* __restrict__ out) {
  int b = blockIdx.x;
  const float* x = logits + b * 1024;
  int tid = threadIdx.x;
  int wave = tid >> 6, lane = tid & 63;
  __shared__ float red[8];

  float m = -1e30f;
  for (int i = tid; i < 1024; i += 256) m = fmaxf(m, x[i]);
  m = wave_max_f(m);
  if (lane == 0) red[wave] = m;
  __syncthreads();
  if (tid == 0) {
    float mm = fmaxf(fmaxf(red[0], red[1]), fmaxf(red[2], red[3]));
    red[4] = mm;
  }
  __syncthreads();
  m = red[4];

  float s = 0.0f;
  for (int i = tid; i < 1024; i += 256) s += expf(x[i] - m);
  s = wave_sum_f(s);
  if (lane == 0) red[wave] = s;
  __syncthreads();
  if (tid == 0) red[5] = logf(red[0] + red[1] + red[2] + red[3]);
  __syncthreads();
  float lse = m + red[5];
  for (int i = tid; i < 1024; i += 256) out[b * 1024 + i] = x[i] - lse;
}

// ---------------- launch ----------------
extern "C" void kernel_launch(void* const* d_in, const int* in_sizes, int n_in,
                              void* d_out, int out_size, void* d_ws, size_t ws_size,
                              hipStream_t stream) {
  const float* leaves = (const float*)d_in[0];
  const float* V_w = (const float*)d_in[1];
  const float* V_b = (const float*)d_in[2];
  const float* U_w = (const float*)d_in[3];
  const float* U_b = (const float*)d_in[4];
  const float* W_w = (const float*)d_in[5];
  const float* W_b = (const float*)d_in[6];
  const float* O_w = (const float*)d_in[7];
  const float* O_b = (const float*)d_in[8];
  float* out = (float*)d_out;

  char* ws = (char*)d_ws;
  size_t off = 0;
  auto alloc = [&](size_t bytes) -> void* {
    off = (off + 255) & ~(size_t)255;
    void* p = ws + off;
    off += bytes;
    return p;
  };

  const size_t MB16 = (size_t)8192 * 1024 * 2;
  bf16_t* leaves_bf = (bf16_t*)alloc(MB16);          // aliased as hB after L0
  bf16_t* Vw_bf  = (bf16_t*)alloc((size_t)1024 * 1024 * 2);
  bf16_t* UW_bf  = (bf16_t*)alloc((size_t)2 * 1024 * 1024 * 2);
  bf16_t* Ow_bf  = (bf16_t*)alloc((size_t)1024 * 1024 * 2);
  float*  buw    = (float*)alloc(1024 * 4);
  bf16_t* hA     = (bf16_t*)alloc(MB16);
  float*  logits = (float*)alloc(8 * 1024 * 4);
  (void)ws_size; (void)in_sizes; (void)n_in; (void)out_size;

  // converts
  k_cvt_bf16<<<(8 * 1024 * 1024 / 4) / 256, 256, 0, stream>>>(leaves, leaves_bf, 8 * 1024 * 1024 / 4);
  k_cvt_bf16<<<(1024 * 1024 / 4) / 256, 256, 0, stream>>>(V_w, Vw_bf, 1024 * 1024 / 4);
  k_cvt_bf16<<<(1024 * 1024 / 4) / 256, 256, 0, stream>>>(O_w, Ow_bf, 1024 * 1024 / 4);
  k_build_uw<<<2048, 256, 0, stream>>>(U_w, W_w, U_b, W_b, UW_bf, buw);

  // layer 0: h = relu(leaves @ V_w^T + V_b)   (8192 x 1024, K=1024)
  k_gemm<<<dim3(8192 / 128, 1024 / 128), 256, 0, stream>>>(leaves_bf, Vw_bf, V_b, hA,
                                                           8192, 1024, 1024);

  // tree levels: one GEMM per level, K=2048 (adjacent-row trick)
  bf16_t* src = hA;
  bf16_t* dst = leaves_bf;   // leaves_bf is dead after L0 -> reuse as ping-pong buffer
  for (int M = 4096; M >= 8; M >>= 1) {
    dim3 g((M + 127) / 128, 1024 / 128);
    k_gemm<<<g, 256, 0, stream>>>(src, UW_bf, buw, dst, M, 2048, 1024);
    bf16_t* t = src; src = dst; dst = t;
  }

  // logits + log_softmax (root = src, 8 x 1024)
  k_logits<<<dim3(4, 8), 256, 0, stream>>>(src, Ow_bf, O_b, logits);
  k_logsoftmax<<<8, 256, 0, stream>>>(logits, out);
}

// Round 2
// 232.745 us; speedup vs baseline: 2.3213x; 2.3213x over previous
//
#include <hip/hip_runtime.h>
#include <hip/hip_bf16.h>
#include <math.h>

typedef __bf16 bf16_t;
typedef __bf16 bf16x8 __attribute__((ext_vector_type(8)));
typedef __bf16 bf16x4 __attribute__((ext_vector_type(4)));
typedef float  f32x4  __attribute__((ext_vector_type(4)));

#define GLD_LDS16(g, l)                                                          \
  __builtin_amdgcn_global_load_lds((const __attribute__((address_space(1))) void*)(g), \
                                   (__attribute__((address_space(3))) void*)(l), 16, 0, 0)

// ---------------- fp32 -> bf16 convert (x4 vectorized) ----------------
__global__ __launch_bounds__(256) void k_cvt_bf16(const float* __restrict__ in,
                                                  bf16_t* __restrict__ out, int n4) {
  int i = blockIdx.x * 256 + threadIdx.x;
  if (i >= n4) return;
  float4 v = reinterpret_cast<const float4*>(in)[i];
  bf16x4 o;
  o[0] = (bf16_t)v.x; o[1] = (bf16_t)v.y; o[2] = (bf16_t)v.z; o[3] = (bf16_t)v.w;
  reinterpret_cast<bf16x4*>(out)[i] = o;
}

// ---------------- build UW = [U_w | W_w] (bf16) + summed bias ----------------
__global__ __launch_bounds__(256) void k_build_uw(const float* __restrict__ U,
                                                  const float* __restrict__ W,
                                                  const float* __restrict__ Ub,
                                                  const float* __restrict__ Wb,
                                                  bf16_t* __restrict__ UW,
                                                  float* __restrict__ buw) {
  int idx = blockIdx.x * 256 + threadIdx.x;
  int i = idx * 4;
  int g = i >> 11;
  int k = i & 2047;
  const float* src = (k < 1024) ? (U + g * 1024 + k) : (W + g * 1024 + (k - 1024));
  float4 v = *reinterpret_cast<const float4*>(src);
  bf16x4 o;
  o[0] = (bf16_t)v.x; o[1] = (bf16_t)v.y; o[2] = (bf16_t)v.z; o[3] = (bf16_t)v.w;
  reinterpret_cast<bf16x4*>(UW)[idx] = o;
  if (idx < 1024) buw[idx] = Ub[idx] + Wb[idx];
}

// ---------------- GEMM: 64x128 tile, BK=32, 2-phase prefetch, optional split-K --------
// C[M,1024] = relu(A[M,K(chunked)] @ Bw[1024,K]^T + bias)  (or fp32 partials to P)
template <int TM, bool SPLIT>
__global__ __launch_bounds__(256) void k_gemm(const bf16_t* __restrict__ A,
                                              const bf16_t* __restrict__ Bw,
                                              const float* __restrict__ bias,
                                              bf16_t* __restrict__ C,
                                              float* __restrict__ P,
                                              int M, int K, int kchunk) {
  constexpr int N = 1024;
  constexpr int MI = TM / 32;                 // row frags per wave
  __shared__ bf16_t As[2][TM * 32];
  __shared__ bf16_t Bs[2][128 * 32];

  const int tid = threadIdx.x;
  const int lane = tid & 63;
  const int wave = tid >> 6;
  const int wr = wave >> 1, wc = wave & 1;
  const int bm = blockIdx.x, bn = blockIdx.y, bz = blockIdx.z;
  const int kbase = bz * kchunk;

  const bf16_t* Abase = A + (size_t)bm * TM * K + kbase;
  const bf16_t* Bbase = Bw + (size_t)bn * 128 * K + kbase;

  f32x4 acc[MI][4] = {};
  const int rl = lane & 15, kq = lane >> 4;

  auto stage = [&](int buf, int ko) {
#pragma unroll
    for (int it = 0; it < TM / 64; ++it) {
      int c = tid + 256 * it;
      int r = c >> 2, kbp = c & 3;
      int kb = kbp ^ ((r >> 1) & 3);          // inverse swizzle on global source
      GLD_LDS16(Abase + (size_t)r * K + ko + kb * 8, &As[buf][c * 8]);
    }
#pragma unroll
    for (int it = 0; it < 2; ++it) {
      int c = tid + 256 * it;
      int r = c >> 2, kbp = c & 3;
      int kb = kbp ^ ((r >> 1) & 3);
      GLD_LDS16(Bbase + (size_t)r * K + ko + kb * 8, &Bs[buf][c * 8]);
    }
  };

  const int kiters = kchunk >> 5;
  stage(0, 0);
  asm volatile("s_waitcnt vmcnt(0)" ::: "memory");
  __builtin_amdgcn_s_barrier();

  for (int t = 0; t < kiters; ++t) {
    const int cur = t & 1;
    if (t + 1 < kiters) stage(cur ^ 1, (t + 1) * 32);   // prefetch overlaps compute
    bf16x8 af[MI], bfr[4];
#pragma unroll
    for (int i = 0; i < MI; ++i) {
      int r = wr * (TM / 2) + i * 16 + rl;
      int kbp = kq ^ ((r >> 1) & 3);
      af[i] = *reinterpret_cast<const bf16x8*>(&As[cur][r * 32 + kbp * 8]);
    }
#pragma unroll
    for (int j = 0; j < 4; ++j) {
      int r = wc * 64 + j * 16 + rl;
      int kbp = kq ^ ((r >> 1) & 3);
      bfr[j] = *reinterpret_cast<const bf16x8*>(&Bs[cur][r * 32 + kbp * 8]);
    }
#pragma unroll
    for (int i = 0; i < MI; ++i)
#pragma unroll
      for (int j = 0; j < 4; ++j)
        acc[i][j] = __builtin_amdgcn_mfma_f32_16x16x32_bf16(af[i], bfr[j], acc[i][j], 0, 0, 0);
    asm volatile("s_waitcnt vmcnt(0)" ::: "memory");
    __builtin_amdgcn_s_barrier();
  }

  const int rq = lane >> 4, cl = lane & 15;
  if (SPLIT) {
    float* Pp = P + (size_t)bz * M * N;
#pragma unroll
    for (int i = 0; i < MI; ++i) {
#pragma unroll
      for (int j = 0; j < 4; ++j) {
        int grow = bm * TM + wr * (TM / 2) + i * 16 + rq * 4;
        int gcol = bn * 128 + wc * 64 + j * 16 + cl;
#pragma unroll
        for (int reg = 0; reg < 4; ++reg)
          Pp[(size_t)(grow + reg) * N + gcol] = acc[i][j][reg];
      }
    }
  } else {
#pragma unroll
    for (int j = 0; j < 4; ++j) {
      int gcol = bn * 128 + wc * 64 + j * 16 + cl;
      float bv = bias[gcol];
#pragma unroll
      for (int i = 0; i < MI; ++i) {
        int grow = bm * TM + wr * (TM / 2) + i * 16 + rq * 4;
#pragma unroll
        for (int reg = 0; reg < 4; ++reg) {
          float v = acc[i][j][reg] + bv;
          v = v > 0.0f ? v : 0.0f;
          C[(size_t)(grow + reg) * N + gcol] = (bf16_t)v;
        }
      }
    }
  }
}

// ---------------- split-K reduce: C = relu(sum_z P[z] + bias), bf16 ----------------
__global__ __launch_bounds__(256) void k_reduce(const float* __restrict__ P,
                                                const float* __restrict__ bias,
                                                bf16_t* __restrict__ C, int M, int ks) {
  constexpr int N = 1024;
  int idx = blockIdx.x * 256 + threadIdx.x;    // over M*N/4
  int col = (idx * 4) & (N - 1);
  int row = (idx * 4) >> 10;
  float4 s = *reinterpret_cast<const float4*>(P + (size_t)row * N + col);
  for (int z = 1; z < ks; ++z) {
    float4 v = *reinterpret_cast<const float4*>(P + ((size_t)z * M + row) * N + col);
    s.x += v.x; s.y += v.y; s.z += v.z; s.w += v.w;
  }
  float4 b = *reinterpret_cast<const float4*>(bias + col);
  bf16x4 o;
  o[0] = (bf16_t)fmaxf(s.x + b.x, 0.0f);
  o[1] = (bf16_t)fmaxf(s.y + b.y, 0.0f);
  o[2] = (bf16_t)fmaxf(s.z + b.z, 0.0f);
  o[3] = (bf16_t)fmaxf(s.w + b.w, 0.0f);
  reinterpret_cast<bf16x4*>(C)[idx] = o;
}

// ---------------- tiny levels (M<=64): wave-per-column GEMV, 8 rows per wave --------
// out[mb..mb+7, n] = relu(A[mb..mb+7,:] . Bw[n,:] + bias[n]); K=2048 fixed.
__global__ __launch_bounds__(256) void k_tail(const bf16_t* __restrict__ A,
                                              const bf16_t* __restrict__ Bw,
                                              const float* __restrict__ bias,
                                              bf16_t* __restrict__ C, int M) {
  constexpr int N = 1024, K = 2048;
  const int lane = threadIdx.x & 63;
  const int gw = blockIdx.x * 4 + (threadIdx.x >> 6);
  const int n = gw & (N - 1);
  const int mbase = (gw >> 10) * 8;
  const int k0 = lane * 32;

  float bv[32];
  const bf16_t* bp = Bw + (size_t)n * K + k0;
#pragma unroll
  for (int q = 0; q < 4; ++q) {
    bf16x8 v = *reinterpret_cast<const bf16x8*>(bp + q * 8);
#pragma unroll
    for (int j = 0; j < 8; ++j) bv[q * 8 + j] = (float)v[j];
  }

  float acc[8];
#pragma unroll
  for (int m = 0; m < 8; ++m) {
    const bf16_t* ap = A + (size_t)(mbase + m) * K + k0;
    float s = 0.0f;
#pragma unroll
    for (int q = 0; q < 4; ++q) {
      bf16x8 v = *reinterpret_cast<const bf16x8*>(ap + q * 8);
#pragma unroll
      for (int j = 0; j < 8; ++j) s += (float)v[j] * bv[q * 8 + j];
    }
    acc[m] = s;
  }
#pragma unroll
  for (int m = 0; m < 8; ++m) {
    acc[m] += __shfl_xor(acc[m], 32, 64);
    acc[m] += __shfl_xor(acc[m], 16, 64);
    acc[m] += __shfl_xor(acc[m], 8, 64);
    acc[m] += __shfl_xor(acc[m], 4, 64);
    acc[m] += __shfl_xor(acc[m], 2, 64);
    acc[m] += __shfl_xor(acc[m], 1, 64);
  }
  if (lane < 8 && mbase + lane < M) {
    float v = acc[lane] + bias[n];
    v = v > 0.0f ? v : 0.0f;
    C[(size_t)(mbase + lane) * N + n] = (bf16_t)v;
  }
}

// ---------------- logits ----------------
__global__ __launch_bounds__(256) void k_logits(const bf16_t* __restrict__ root,
                                                const bf16_t* __restrict__ Ow,
                                                const float* __restrict__ Ob,
                                                float* __restrict__ out) {
  int o = blockIdx.x * 256 + threadIdx.x;
  int b = blockIdx.y;
  const bf16_t* r = root + b * 1024;
  const bf16_t* w = Ow + (size_t)o * 1024;
  float s = 0.0f;
#pragma unroll 4
  for (int k = 0; k < 1024; k += 8) {
    bf16x8 rv = *reinterpret_cast<const bf16x8*>(r + k);
    bf16x8 wv = *reinterpret_cast<const bf16x8*>(w + k);
#pragma unroll
    for (int j = 0; j < 8; ++j) s += (float)rv[j] * (float)wv[j];
  }
  out[b * 1024 + o] = s + Ob[o];
}

// ---------------- log_softmax ----------------
__device__ inline float wave_max_f(float v) {
#pragma unroll
  for (int off = 32; off > 0; off >>= 1) v = fmaxf(v, __shfl_xor(v, off, 64));
  return v;
}
__device__ inline float wave_sum_f(float v) {
#pragma unroll
  for (int off = 32; off > 0; off >>= 1) v += __shfl_xor(v, off, 64);
  return v;
}

__global__ __launch_bounds__(256) void k_logsoftmax(const float* __restrict__ logits,
                                                    float* __restrict__ out) {
  int b = blockIdx.x;
  const float* x = logits + b * 1024;
  int tid = threadIdx.x;
  int wave = tid >> 6, lane = tid & 63;
  __shared__ float red[8];

  float m = -1e30f;
  for (int i = tid; i < 1024; i += 256) m = fmaxf(m, x[i]);
  m = wave_max_f(m);
  if (lane == 0) red[wave] = m;
  __syncthreads();
  if (tid == 0) red[4] = fmaxf(fmaxf(red[0], red[1]), fmaxf(red[2], red[3]));
  __syncthreads();
  m = red[4];

  float s = 0.0f;
  for (int i = tid; i < 1024; i += 256) s += expf(x[i] - m);
  s = wave_sum_f(s);
  if (lane == 0) red[wave] = s;
  __syncthreads();
  if (tid == 0) red[5] = logf(red[0] + red[1] + red[2] + red[3]);
  __syncthreads();
  float lse = m + red[5];
  for (int i = tid; i < 1024; i += 256) out[b * 1024 + i] = x[i] - lse;
}

// ---------------- launch ----------------
extern "C" void kernel_launch(void* const* d_in, const int* in_sizes, int n_in,
                              void* d_out, int out_size, void* d_ws, size_t ws_size,
                              hipStream_t stream) {
  const float* leaves = (const float*)d_in[0];
  const float* V_w = (const float*)d_in[1];
  const float* V_b = (const float*)d_in[2];
  const float* U_w = (const float*)d_in[3];
  const float* U_b = (const float*)d_in[4];
  const float* W_w = (const float*)d_in[5];
  const float* W_b = (const float*)d_in[6];
  const float* O_w = (const float*)d_in[7];
  const float* O_b = (const float*)d_in[8];
  float* out = (float*)d_out;

  char* ws = (char*)d_ws;
  size_t off = 0;
  auto alloc = [&](size_t bytes) -> void* {
    off = (off + 255) & ~(size_t)255;
    void* p = ws + off;
    off += bytes;
    return p;
  };

  const size_t MB16 = (size_t)8192 * 1024 * 2;
  bf16_t* leaves_bf = (bf16_t*)alloc(MB16);
  bf16_t* Vw_bf = (bf16_t*)alloc((size_t)1024 * 1024 * 2);
  bf16_t* UW_bf = (bf16_t*)alloc((size_t)2 * 1024 * 1024 * 2);
  bf16_t* Ow_bf = (bf16_t*)alloc((size_t)1024 * 1024 * 2);
  float* buw = (float*)alloc(1024 * 4);
  bf16_t* hA = (bf16_t*)alloc(MB16);
  float* logits = (float*)alloc(8 * 1024 * 4);
  float* Pbuf = (float*)alloc((size_t)4 * 2048 * 1024 * 4);   // 16 MB fp32 partials
  (void)ws_size; (void)in_sizes; (void)n_in; (void)out_size;

  k_cvt_bf16<<<(8 * 1024 * 1024 / 4) / 256, 256, 0, stream>>>(leaves, leaves_bf, 8 * 1024 * 1024 / 4);
  k_cvt_bf16<<<(1024 * 1024 / 4) / 256, 256, 0, stream>>>(V_w, Vw_bf, 1024 * 1024 / 4);
  k_cvt_bf16<<<(1024 * 1024 / 4) / 256, 256, 0, stream>>>(O_w, Ow_bf, 1024 * 1024 / 4);
  k_build_uw<<<2048, 256, 0, stream>>>(U_w, W_w, U_b, W_b, UW_bf, buw);

  // L0: 8192x1024, K=1024 -> 128x8 = 1024 blocks
  k_gemm<64, false><<<dim3(128, 8), 256, 0, stream>>>(leaves_bf, Vw_bf, V_b, hA, nullptr,
                                                      8192, 1024, 1024);

  bf16_t* src = hA;
  bf16_t* dst = leaves_bf;
  auto swap = [&]() { bf16_t* t = src; src = dst; dst = t; };

  // M=4096, K=2048, no split: 64x8 = 512 blocks
  k_gemm<64, false><<<dim3(64, 8), 256, 0, stream>>>(src, UW_bf, buw, dst, nullptr,
                                                     4096, 2048, 2048);
  swap();
  // M=2048: split-K 2 (chunk 1024) -> 512 blocks
  k_gemm<64, true><<<dim3(32, 8, 2), 256, 0, stream>>>(src, UW_bf, nullptr, nullptr, Pbuf,
                                                       2048, 2048, 1024);
  k_reduce<<<2048 * 1024 / 4 / 256, 256, 0, stream>>>(Pbuf, buw, dst, 2048, 2);
  swap();
  // M=1024: split-K 4 (chunk 512) -> 512 blocks
  k_gemm<64, true><<<dim3(16, 8, 4), 256, 0, stream>>>(src, UW_bf, nullptr, nullptr, Pbuf,
                                                       1024, 2048, 512);
  k_reduce<<<1024 * 1024 / 4 / 256, 256, 0, stream>>>(Pbuf, buw, dst, 1024, 4);
  swap();
  // M=512: split-K 4 (chunk 512) -> 256 blocks
  k_gemm<64, true><<<dim3(8, 8, 4), 256, 0, stream>>>(src, UW_bf, nullptr, nullptr, Pbuf,
                                                      512, 2048, 512);
  k_reduce<<<512 * 1024 / 4 / 256, 256, 0, stream>>>(Pbuf, buw, dst, 512, 4);
  swap();
  // M=256: split-K 8 (chunk 256) -> 256 blocks
  k_gemm<64, true><<<dim3(4, 8, 8), 256, 0, stream>>>(src, UW_bf, nullptr, nullptr, Pbuf,
                                                      256, 2048, 256);
  k_reduce<<<256 * 1024 / 4 / 256, 256, 0, stream>>>(Pbuf, buw, dst, 256, 8);
  swap();
  // M=128: split-K 8 (chunk 256) -> 128 blocks
  k_gemm<64, true><<<dim3(2, 8, 8), 256, 0, stream>>>(src, UW_bf, nullptr, nullptr, Pbuf,
                                                      128, 2048, 256);
  k_reduce<<<128 * 1024 / 4 / 256, 256, 0, stream>>>(Pbuf, buw, dst, 128, 8);
  swap();
  // M = 64, 32, 16, 8: GEMV tail (wave per column, 8 rows per wave)
  for (int M = 64; M >= 8; M >>= 1) {
    int blocks = (M / 8) * 1024 / 4;
    k_tail<<<blocks, 256, 0, stream>>>(src, UW_bf, buw, dst, M);
    swap();
  }

  k_logits<<<dim3(4, 8), 256, 0, stream>>>(src, Ow_bf, O_b, logits);
  k_logsoftmax<<<8, 256, 0, stream>>>(logits, out);
}